// Round 4
// baseline (1753.732 us; speedup 1.0000x reference)
//
#include <hip/hip_runtime.h>
#include <stdint.h>

// ---------------- problem constants ----------------
static constexpr int Hd   = 1024;     // H_DIM
static constexpr int BZn  = 256;      // batch
static constexpr int MTOT = 131072;   // 32 * 4096 keys
static constexpr int BM   = 32;       // key rows per block (main kernel)
static constexpr int NU   = 7;        // units

typedef float  f32x16 __attribute__((ext_vector_type(16)));
typedef short  bf16x8 __attribute__((ext_vector_type(8)));
typedef unsigned short u16;

__device__ __forceinline__ u16 f2bf(float f) {
    unsigned int u = __float_as_uint(f);
    unsigned int r = (u + 0x7FFFu + ((u >> 16) & 1u)) >> 16;  // RNE
    return (u16)r;
}
__device__ __forceinline__ float bf2f(u16 h) {
    return __uint_as_float(((unsigned int)h) << 16);
}

// ---------------- prep kernels ----------------

// Qrot[256][1024] = query @ R  (f32). 64 blocks x 4 rows.
__global__ void k_qrot(const float* __restrict__ query, const float* __restrict__ R,
                       float* __restrict__ Qrot) {
    __shared__ float qt[4][Hd];
    const int t = threadIdx.x;
    const int r0 = blockIdx.x * 4;
    for (int r = 0; r < 4; ++r)
        *(float4*)(&qt[r][t * 4]) = *(const float4*)(query + (long long)(r0 + r) * Hd + t * 4);
    __syncthreads();
    float acc[4][4] = {};
    for (int k = 0; k < Hd; ++k) {
        float4 rv = *(const float4*)(R + (long long)k * Hd + t * 4);
#pragma unroll
        for (int r = 0; r < 4; ++r) {
            float qv = qt[r][k];
            acc[r][0] += qv * rv.x; acc[r][1] += qv * rv.y;
            acc[r][2] += qv * rv.z; acc[r][3] += qv * rv.w;
        }
    }
    for (int r = 0; r < 4; ++r) {
        float4 o; o.x = acc[r][0]; o.y = acc[r][1]; o.z = acc[r][2]; o.w = acc[r][3];
        *(float4*)(Qrot + (long long)(r0 + r) * Hd + t * 4) = o;
    }
}

// Rpack32: B-fragment layout for mfma_f32_32x32x16_bf16.
// frag id = (c0/32)*64 + (k0/16); lane l holds B[k0+(l>>5)*8+j][c0+(l&31)], j=0..7.
// 2048 frags. 512 blocks x 256 threads.
__global__ void k_rpack32(const float* __restrict__ R, u16* __restrict__ Rp) {
    const int gt = blockIdx.x * 256 + threadIdx.x;
    const int f = gt >> 6, l = gt & 63;
    const int cblk = f >> 6, kblk = f & 63;
    const int col = cblk * 32 + (l & 31);
    const int k0  = kblk * 16 + (l >> 5) * 8;
    union { bf16x8 v; u16 u[8]; } p;
#pragma unroll
    for (int j = 0; j < 8; ++j) p.u[j] = f2bf(R[(long long)(k0 + j) * Hd + col]);
    *(bf16x8*)(Rp + (long long)f * 512 + l * 8) = p.v;
}

// Qpack32: A-fragment layout for mfma_f32_32x32x16_bf16.
// frag id = (k0/16)*8 + (b0/32); lane l holds A[b0+(l&31)][k0+(l>>5)*8+j].
// 512 frags. 128 blocks x 256 threads.
__global__ void k_qpack32(const float* __restrict__ Qrot, u16* __restrict__ Qp) {
    const int gt = blockIdx.x * 256 + threadIdx.x;
    const int f = gt >> 6, l = gt & 63;
    const int kblk = f >> 3, bblk = f & 7;
    const int b  = bblk * 32 + (l & 31);
    const int k0 = kblk * 16 + (l >> 5) * 8;
    union { bf16x8 v; u16 u[8]; } p;
#pragma unroll
    for (int j = 0; j < 8; ++j) p.u[j] = f2bf(Qrot[(long long)b * Hd + k0 + j]);
    *(bf16x8*)(Qp + (long long)f * 512 + l * 8) = p.v;
}

// ---------------- fused main kernel (512 threads = 8 waves, 2 blocks/CU) ----------------
// LDS: keysA[65536] | Krot[16384]  = 81920 B exactly -> 2 blocks/CU
static constexpr int LDS_TOT = 81920;

__global__ __launch_bounds__(512, 4)
void k_main(const float* __restrict__ keys, const u16* __restrict__ Rp,
            const u16* __restrict__ Qp, unsigned long long* __restrict__ best) {
    extern __shared__ char smem[];
    char* keysA = smem;
    char* Krot  = smem + 65536;

    const int t   = threadIdx.x;
    const int lam = t & 63;
    const int w   = t >> 6;          // 8 waves; wave = one 32-col group per sc
    const int l31 = lam & 31;
    const int hi  = lam >> 5;
    const int row0 = blockIdx.x * BM;

    // ---- stage this block's 32 key rows: f32 -> bf16, swizzled ----
    {
        const float* kb = keys + (long long)row0 * Hd;
#pragma unroll
        for (int i = 0; i < 8; ++i) {
            int e0 = i * 4096 + t * 8;
            float4 v0 = *(const float4*)(kb + e0);
            float4 v1 = *(const float4*)(kb + e0 + 4);
            int row = e0 >> 10, k = e0 & 1023;
            union { bf16x8 v; u16 u[8]; } p;
            p.u[0] = f2bf(v0.x); p.u[1] = f2bf(v0.y); p.u[2] = f2bf(v0.z); p.u[3] = f2bf(v0.w);
            p.u[4] = f2bf(v1.x); p.u[5] = f2bf(v1.y); p.u[6] = f2bf(v1.z); p.u[7] = f2bf(v1.w);
            int byte = (row * 2048 + k * 2) ^ ((row & 7) << 4);
            *(bf16x8*)(keysA + byte) = p.v;
        }
    }
    __syncthreads();

    const char* RpB = (const char*)Rp;
    const char* QpB = (const char*)Qp;

    const int arow  = l31;
    const int aswz  = (arow & 7) << 4;
    const int abase = arow * 2048 + hi * 16;

#pragma unroll
    for (int sc = 0; sc < 4; ++sc) {
        // ==== rotation: racc[key 0..31][col = sc*256 + w*32 + (l&31)] ====
        f32x16 racc;
#pragma unroll
        for (int j = 0; j < 16; ++j) racc[j] = 0.f;

        const char* bb = RpB + (long long)((sc * 8 + w) * 64) * 1024 + lam * 16;

        bf16x8 nb[4];
#pragma unroll
        for (int j = 0; j < 4; ++j) nb[j] = *(const bf16x8*)(bb + j * 1024);

#pragma unroll 4
        for (int ks4 = 0; ks4 < 16; ++ks4) {
            bf16x8 cb[4];
#pragma unroll
            for (int j = 0; j < 4; ++j) cb[j] = nb[j];
            if (ks4 < 15) {
#pragma unroll
                for (int j = 0; j < 4; ++j)
                    nb[j] = *(const bf16x8*)(bb + ((ks4 + 1) * 4 + j) * 1024);
            }
#pragma unroll
            for (int j = 0; j < 4; ++j) {
                int abyte = (abase + (ks4 * 4 + j) * 32) ^ aswz;
                bf16x8 a = *(const bf16x8*)(keysA + abyte);
                racc = __builtin_amdgcn_mfma_f32_32x32x16_bf16(a, cb[j], racc, 0, 0, 0);
            }
        }

        __syncthreads();   // prev sc's sims finished reading Krot

        // ---- write Krot tile [32 keys][256 cols] bf16, swizzled ----
#pragma unroll
        for (int r = 0; r < 16; ++r) {
            int key = (r & 3) + 8 * (r >> 2) + 4 * hi;
            int byte = (key * 512 + (w * 32 + l31) * 2) ^ ((key & 7) << 4);
            *(u16*)(Krot + byte) = f2bf(racc[r]);
        }
        __syncthreads();   // Krot visible

        // ==== sims: acc[batch][key] over this sc's 256 cols, unit-segmented ====
        f32x16 acc;
#pragma unroll
        for (int j = 0; j < 16; ++j) acc[j] = 0.f;
        float nrm = 0.f;

        const char* qb = QpB + (long long)((sc * 16) * 8 + w) * 1024 + lam * 16;
        bf16x8 aq0 = *(const bf16x8*)(qb);
        bf16x8 aq1 = *(const bf16x8*)(qb + 8192);

        const int fm = (sc < 2) ? 0x8000 : (sc == 2) ? 0x8080 : 0x8880;
        int u = (sc < 2) ? sc : (sc == 2) ? 2 : 4;

#pragma unroll
        for (int step = 0; step < 16; ++step) {
            int bbyte = (l31 * 512 + (step * 16 + hi * 8) * 2) ^ ((l31 & 7) << 4);
            bf16x8 bk = *(const bf16x8*)(Krot + bbyte);
            bf16x8 a = (step & 1) ? aq1 : aq0;
            if (step < 14) {
                bf16x8 nxt = *(const bf16x8*)(qb + (step + 2) * 8192);
                if (step & 1) aq1 = nxt; else aq0 = nxt;
            }
            acc = __builtin_amdgcn_mfma_f32_32x32x16_bf16(a, bk, acc, 0, 0, 0);

            // per-key norm partial from the bf16 Krot values this lane just read
            union { bf16x8 v; u16 s[8]; } ub; ub.v = bk;
#pragma unroll
            for (int j = 0; j < 8; ++j) { float f = bf2f(ub.s[j]); nrm = fmaf(f, f, nrm); }

            if ((fm >> step) & 1) {
                // ---- flush unit u: scale, argmax over 32 keys, atomic ----
                float ntot = nrm + __shfl_xor(nrm, 32);
                float inv  = 1.0f / fmaxf(sqrtf(ntot), 1e-3f);
                float bv[16]; int ki[16];
#pragma unroll
                for (int r = 0; r < 16; ++r) { bv[r] = acc[r] * inv; ki[r] = row0 + l31; }
#pragma unroll
                for (int mask = 1; mask <= 16; mask <<= 1) {
#pragma unroll
                    for (int r = 0; r < 16; ++r) {
                        float ov = __shfl_xor(bv[r], mask);
                        int   oi = __shfl_xor(ki[r], mask);
                        if (ov > bv[r] || (ov == bv[r] && oi < ki[r])) { bv[r] = ov; ki[r] = oi; }
                    }
                }
                if (l31 == 0) {
#pragma unroll
                    for (int r = 0; r < 16; ++r) {
                        int q = w * 32 + (r & 3) + 8 * (r >> 2) + 4 * hi;
                        unsigned int ui = __float_as_uint(bv[r]);
                        unsigned int mp = ui ^ ((ui >> 31) ? 0xFFFFFFFFu : 0x80000000u);
                        unsigned long long enc =
                            ((unsigned long long)mp << 32) |
                            (unsigned long long)(0xFFFFFFFFu - (unsigned int)ki[r]);
                        unsigned long long* addr = best + u * BZn + q;
                        if (enc > *addr) atomicMax(addr, enc);
                    }
                }
#pragma unroll
                for (int j = 0; j < 16; ++j) acc[j] = 0.f;
                nrm = 0.f;
                ++u;
            }
        }
    }
}

// ---------------- finish: exact f32 cosine of the winners ----------------
__global__ void k_final(const float* __restrict__ keys, const float* __restrict__ R,
                        const float* __restrict__ Qrot,
                        const unsigned long long* __restrict__ best, float* __restrict__ out) {
    const int fid = blockIdx.x;
    const int u = fid >> 8, b = fid & 255;
    int off, d;
    if (u < 2)      { off = u * 256;            d = 256; }
    else if (u < 5) { off = 512 + (u - 2) * 128; d = 128; }
    else            { off = 896 + (u - 5) * 64;  d = 64;  }

    unsigned long long ent = best[fid];
    if (ent == 0ull) return;  // no winner -> zero vector -> cos = 0

    __shared__ float krow[Hd];
    __shared__ float red[12];
    const int t = threadIdx.x;
    unsigned int gl = 0xFFFFFFFFu - (unsigned int)(ent & 0xFFFFFFFFull);
    const float* kp = keys + (long long)gl * Hd;
    *(float4*)(&krow[t * 4]) = *(const float4*)(kp + t * 4);
    __syncthreads();

    float pn = 0.f, pq = 0.f, pk = 0.f;
    if (t < d) {
        float kr = 0.f;
        for (int k = 0; k < Hd; ++k) kr += krow[k] * R[(long long)k * Hd + off + t];
        float qv = Qrot[(long long)b * Hd + off + t];
        pn = qv * kr; pq = qv * qv; pk = kr * kr;
    }
    for (int mask = 1; mask <= 32; mask <<= 1) {
        pn += __shfl_xor(pn, mask); pq += __shfl_xor(pq, mask); pk += __shfl_xor(pk, mask);
    }
    if ((t & 63) == 0) { red[t >> 6] = pn; red[4 + (t >> 6)] = pq; red[8 + (t >> 6)] = pk; }
    __syncthreads();
    if (t == 0) {
        float nm = red[0] + red[1] + red[2] + red[3];
        float qq = red[4] + red[5] + red[6] + red[7];
        float kk = red[8] + red[9] + red[10] + red[11];
        float cosv = nm / (fmaxf(sqrtf(qq), 1e-8f) * fmaxf(sqrtf(kk), 1e-8f));
        atomicAdd(out, -cosv * (float)d / (256.0f * 1024.0f));
    }
}

// ---------------- launch ----------------
extern "C" void kernel_launch(void* const* d_in, const int* in_sizes, int n_in,
                              void* d_out, int out_size, void* d_ws, size_t ws_size,
                              hipStream_t stream) {
    (void)in_sizes; (void)n_in; (void)out_size; (void)ws_size;
    const float* query = (const float*)d_in[0];
    const float* keys  = (const float*)d_in[1];
    const float* R     = (const float*)d_in[2];
    float* out = (float*)d_out;
    char* ws = (char*)d_ws;

    unsigned long long* best = (unsigned long long*)ws;          // 14336 B (pad 16384)
    float* Qrot   = (float*)(ws + 16384);                        // 1 MiB
    u16*   Rpack  = (u16*)(ws + 16384 + 1048576);                // 2 MiB
    u16*   Qpack  = (u16*)(ws + 16384 + 1048576 + 2097152);      // 512 KiB

    hipMemsetAsync(best, 0, NU * BZn * sizeof(unsigned long long), stream);
    hipMemsetAsync(out, 0, sizeof(float), stream);

    k_qrot   <<<64,  256, 0, stream>>>(query, R, Qrot);
    k_rpack32<<<512, 256, 0, stream>>>(R, Rpack);
    k_qpack32<<<128, 256, 0, stream>>>(Qrot, Qpack);

    hipFuncSetAttribute((const void*)k_main,
                        hipFuncAttributeMaxDynamicSharedMemorySize, LDS_TOT);
    k_main <<<MTOT / BM, 512, LDS_TOT, stream>>>(keys, Rpack, Qpack, best);
    k_final<<<NU * BZn, 256, 0, stream>>>(keys, R, Qrot, best, out);
}

// Round 5
// 1125.910 us; speedup vs baseline: 1.5576x; 1.5576x over previous
//
#include <hip/hip_runtime.h>
#include <stdint.h>

// ---------------- problem constants ----------------
static constexpr int Hd   = 1024;     // H_DIM
static constexpr int BZn  = 256;      // batch
static constexpr int MTOT = 131072;   // 32 * 4096 keys
static constexpr int BM   = 64;       // key rows per block (main kernel)
static constexpr int NU   = 7;        // units

typedef float  f32x4  __attribute__((ext_vector_type(4)));
typedef short  bf16x8 __attribute__((ext_vector_type(8)));
typedef unsigned short u16;

__device__ __forceinline__ u16 f2bf(float f) {
    unsigned int u = __float_as_uint(f);
    unsigned int r = (u + 0x7FFFu + ((u >> 16) & 1u)) >> 16;  // RNE
    return (u16)r;
}
__device__ __forceinline__ float bf2f(u16 h) {
    return __uint_as_float(((unsigned int)h) << 16);
}

// ---------------- prep kernels ----------------

// Qrot[256][1024] = query @ R  (f32). 64 blocks x 4 rows.
__global__ void k_qrot(const float* __restrict__ query, const float* __restrict__ R,
                       float* __restrict__ Qrot) {
    __shared__ float qt[4][Hd];
    const int t = threadIdx.x;
    const int r0 = blockIdx.x * 4;
    for (int r = 0; r < 4; ++r)
        *(float4*)(&qt[r][t * 4]) = *(const float4*)(query + (long long)(r0 + r) * Hd + t * 4);
    __syncthreads();
    float acc[4][4] = {};
    for (int k = 0; k < Hd; ++k) {
        float4 rv = *(const float4*)(R + (long long)k * Hd + t * 4);
#pragma unroll
        for (int r = 0; r < 4; ++r) {
            float qv = qt[r][k];
            acc[r][0] += qv * rv.x; acc[r][1] += qv * rv.y;
            acc[r][2] += qv * rv.z; acc[r][3] += qv * rv.w;
        }
    }
    for (int r = 0; r < 4; ++r) {
        float4 o; o.x = acc[r][0]; o.y = acc[r][1]; o.z = acc[r][2]; o.w = acc[r][3];
        *(float4*)(Qrot + (long long)(r0 + r) * Hd + t * 4) = o;
    }
}

// Rpack: B-fragment layout for mfma_f32_16x16x32_bf16.
// frag id = (c0/16)*32 + (k0/32); lane l holds B[k0+(l>>4)*8+j][c0+(l&15)], j=0..7.
__global__ void k_rpack(const float* __restrict__ R, u16* __restrict__ Rpack) {
    const int gt = blockIdx.x * 256 + threadIdx.x;
    const int frag = gt >> 6, lam = gt & 63;
    const int cblk = frag >> 5, kblk = frag & 31;
    const int c  = cblk * 16 + (lam & 15);
    const int k0 = kblk * 32 + (lam >> 4) * 8;
    union { bf16x8 v; u16 u[8]; } p;
#pragma unroll
    for (int j = 0; j < 8; ++j) p.u[j] = f2bf(R[(long long)(k0 + j) * Hd + c]);
    *(bf16x8*)(Rpack + (long long)frag * 512 + lam * 8) = p.v;
}

// Qpack: A-fragment layout. frag id = (c0/32)*16 + (q0/16);
// lane l holds A[q0+(l&15)][c0+(l>>4)*8+j].
__global__ void k_qpack(const float* __restrict__ Qrot, u16* __restrict__ Qpack) {
    const int gt = blockIdx.x * 256 + threadIdx.x;
    const int frag = gt >> 6, lam = gt & 63;
    const int cblk = frag >> 4, qblk = frag & 15;
    const int q  = qblk * 16 + (lam & 15);
    const int c0 = cblk * 32 + (lam >> 4) * 8;
    union { bf16x8 v; u16 u[8]; } p;
#pragma unroll
    for (int j = 0; j < 8; ++j) p.u[j] = f2bf(Qrot[(long long)q * Hd + c0 + j]);
    *(bf16x8*)(Qpack + (long long)frag * 512 + lam * 8) = p.v;
}

// ---------------- fused main kernel (512 threads = 8 waves) ----------------
// LDS: keysA[131072] | Krot[32768] = 163840 B (exactly 160 KiB, 1 block/CU)
static constexpr int LDS_TOT = 163840;

__global__ __launch_bounds__(512, 2)
void k_main(const float* __restrict__ keys, const u16* __restrict__ Rp,
            const u16* __restrict__ Qp, unsigned long long* __restrict__ best) {
    extern __shared__ char smem[];
    char* keysA = smem;
    char* Krot  = smem + 131072;   // [64 keys][256 cols] bf16, swizzled

    const int t   = threadIdx.x;
    const int lam = t & 63;
    const int w   = t >> 6;          // 8 waves
    const int l15 = lam & 15;
    const int lg  = lam >> 4;
    const int row0 = blockIdx.x * BM;

    // ---- stage this block's 64 key rows: f32 -> bf16, swizzled ----
    {
        const float* kb = keys + (long long)row0 * Hd;
#pragma unroll 4
        for (int i = 0; i < 16; ++i) {
            int e0 = i * 4096 + t * 8;
            float4 v0 = *(const float4*)(kb + e0);
            float4 v1 = *(const float4*)(kb + e0 + 4);
            int row = e0 >> 10, k = e0 & 1023;
            union { bf16x8 v; u16 u[8]; } p;
            p.u[0] = f2bf(v0.x); p.u[1] = f2bf(v0.y); p.u[2] = f2bf(v0.z); p.u[3] = f2bf(v0.w);
            p.u[4] = f2bf(v1.x); p.u[5] = f2bf(v1.y); p.u[6] = f2bf(v1.z); p.u[7] = f2bf(v1.w);
            int byte = (row * 2048 + k * 2) ^ ((row & 7) << 4);
            *(bf16x8*)(keysA + byte) = p.v;
        }
    }
    __syncthreads();

    const char* RpB = (const char*)Rp;
    const int aswz = (l15 & 7) << 4;

#pragma unroll 1
    for (int q = 0; q < 4; ++q) {
        // ==== rotation: wave w owns cols q*256 + w*32 + [0,32); all 64 keys ====
        // B-frag stream: frag = cblk*32 + ks, cblk = q*16 + w*2 + n2; 1024 B/frag.
        const char* bb0 = RpB + (long long)(q * 16 + w * 2 + 0) * 32768 + lam * 16;
        const char* bb1 = RpB + (long long)(q * 16 + w * 2 + 1) * 32768 + lam * 16;

        f32x4 racc[4][2];
#pragma unroll
        for (int m = 0; m < 4; ++m) { racc[m][0] = (f32x4){0,0,0,0}; racc[m][1] = (f32x4){0,0,0,0}; }

        // depth-2 B prefetch ring
        bf16x8 nbA0 = *(const bf16x8*)(bb0);
        bf16x8 nbA1 = *(const bf16x8*)(bb1);
        bf16x8 nbB0 = *(const bf16x8*)(bb0 + 1024);
        bf16x8 nbB1 = *(const bf16x8*)(bb1 + 1024);

#pragma unroll 4
        for (int ks = 0; ks < 32; ++ks) {
            bf16x8 cb0 = nbA0, cb1 = nbA1;
            nbA0 = nbB0; nbA1 = nbB1;
            if (ks < 30) {
                nbB0 = *(const bf16x8*)(bb0 + (ks + 2) * 1024);
                nbB1 = *(const bf16x8*)(bb1 + (ks + 2) * 1024);
            }
#pragma unroll
            for (int m = 0; m < 4; ++m) {
                int abyte = ((m * 16 + l15) * 2048 + (ks * 32 + lg * 8) * 2) ^ aswz;
                bf16x8 a = *(const bf16x8*)(keysA + abyte);
                racc[m][0] = __builtin_amdgcn_mfma_f32_16x16x32_bf16(a, cb0, racc[m][0], 0, 0, 0);
                racc[m][1] = __builtin_amdgcn_mfma_f32_16x16x32_bf16(a, cb1, racc[m][1], 0, 0, 0);
            }
        }

        __syncthreads();   // previous quarter's sims done reading Krot

        // ---- write Krot [64 keys][256 cols] bf16, swizzled ----
#pragma unroll
        for (int m = 0; m < 4; ++m)
#pragma unroll
            for (int n2 = 0; n2 < 2; ++n2) {
                int qcol = w * 32 + n2 * 16 + l15;
#pragma unroll
                for (int e = 0; e < 4; ++e) {
                    int key = m * 16 + lg * 4 + e;
                    int byte = (key * 512 + qcol * 2) ^ ((key & 7) << 4);
                    *(u16*)(Krot + byte) = f2bf(racc[m][n2][e]);
                }
            }
        __syncthreads();   // Krot visible

        // ==== sims: wave w owns queries w*32 + [0,32); keys 0..63; 8 ksteps of 32 cols ====
        const int ubase = (q == 0) ? 0 : (q == 1) ? 1 : (q == 2) ? 2 : 4;
        const int fmask = (q < 2) ? 0x80 : (q == 2) ? 0x88 : 0xA8;

        f32x4 acc[2][4];
#pragma unroll
        for (int m = 0; m < 2; ++m)
#pragma unroll
            for (int n = 0; n < 4; ++n) acc[m][n] = (f32x4){0,0,0,0};
        float nrm[4] = {0.f, 0.f, 0.f, 0.f};
        int u = ubase;

#pragma unroll
        for (int ks = 0; ks < 8; ++ks) {
            bf16x8 aq[2], bk[4];
            int cblk = q * 8 + ks;
#pragma unroll
            for (int m = 0; m < 2; ++m) {
                long long qoff = ((long long)(cblk * 16 + (w * 2 + m)) * 64 + lam) * 8;
                aq[m] = *(const bf16x8*)(Qp + qoff);
            }
#pragma unroll
            for (int n = 0; n < 4; ++n) {
                int byte = ((n * 16 + l15) * 512 + (ks * 32 + lg * 8) * 2) ^ aswz;
                bk[n] = *(const bf16x8*)(Krot + byte);
            }
#pragma unroll
            for (int m = 0; m < 2; ++m)
#pragma unroll
                for (int n = 0; n < 4; ++n)
                    acc[m][n] = __builtin_amdgcn_mfma_f32_16x16x32_bf16(aq[m], bk[n], acc[m][n], 0, 0, 0);
            // per-key norm partials from the bf16 Krot values just read
#pragma unroll
            for (int n = 0; n < 4; ++n) {
                union { bf16x8 v; u16 s[8]; } ub; ub.v = bk[n];
#pragma unroll
                for (int j = 0; j < 8; ++j) { float f = bf2f(ub.s[j]); nrm[n] = fmaf(f, f, nrm[n]); }
            }

            if ((fmask >> ks) & 1) {
                // ---- flush unit u: combine norms across lg, scale, argmax, atomic ----
                float rn[4];
#pragma unroll
                for (int n = 0; n < 4; ++n) {
                    float s = nrm[n];
                    s += __shfl_xor(s, 16);
                    s += __shfl_xor(s, 32);
                    rn[n] = 1.0f / fmaxf(sqrtf(s), 1e-3f);
                    nrm[n] = 0.f;
                }
#pragma unroll
                for (int m = 0; m < 2; ++m) {
#pragma unroll
                    for (int e = 0; e < 4; ++e) {
                        float bv = acc[m][0][e] * rn[0];
                        int   bi = l15;
#pragma unroll
                        for (int n = 1; n < 4; ++n) {
                            float v = acc[m][n][e] * rn[n];
                            if (v > bv) { bv = v; bi = n * 16 + l15; }
                        }
#pragma unroll
                        for (int mask = 1; mask <= 8; mask <<= 1) {
                            float ov = __shfl_xor(bv, mask);
                            int   oi = __shfl_xor(bi, mask);
                            if (ov > bv || (ov == bv && oi < bi)) { bv = ov; bi = oi; }
                        }
                        if (l15 == 0) {
                            int qq = w * 32 + m * 16 + lg * 4 + e;
                            unsigned int ui = __float_as_uint(bv);
                            unsigned int mp = ui ^ ((ui >> 31) ? 0xFFFFFFFFu : 0x80000000u);
                            unsigned int gl = (unsigned int)(row0 + bi);
                            unsigned long long enc =
                                ((unsigned long long)mp << 32) |
                                (unsigned long long)(0xFFFFFFFFu - gl);
                            unsigned long long* addr = best + u * BZn + qq;
                            if (enc > *addr) atomicMax(addr, enc);
                        }
                    }
#pragma unroll
                    for (int n = 0; n < 4; ++n) acc[m][n] = (f32x4){0,0,0,0};
                }
                ++u;
            }
        }
    }
}

// ---------------- finish: exact f32 cosine of the winners ----------------
__global__ void k_final(const float* __restrict__ keys, const float* __restrict__ R,
                        const float* __restrict__ Qrot,
                        const unsigned long long* __restrict__ best, float* __restrict__ out) {
    const int fid = blockIdx.x;
    const int u = fid >> 8, b = fid & 255;
    int off, d;
    if (u < 2)      { off = u * 256;            d = 256; }
    else if (u < 5) { off = 512 + (u - 2) * 128; d = 128; }
    else            { off = 896 + (u - 5) * 64;  d = 64;  }

    unsigned long long ent = best[fid];
    if (ent == 0ull) return;  // no winner -> zero vector -> cos = 0

    __shared__ float krow[Hd];
    __shared__ float red[12];
    const int t = threadIdx.x;
    unsigned int gl = 0xFFFFFFFFu - (unsigned int)(ent & 0xFFFFFFFFull);
    const float* kp = keys + (long long)gl * Hd;
    *(float4*)(&krow[t * 4]) = *(const float4*)(kp + t * 4);
    __syncthreads();

    float pn = 0.f, pq = 0.f, pk = 0.f;
    if (t < d) {
        float kr = 0.f;
        for (int k = 0; k < Hd; ++k) kr += krow[k] * R[(long long)k * Hd + off + t];
        float qv = Qrot[(long long)b * Hd + off + t];
        pn = qv * kr; pq = qv * qv; pk = kr * kr;
    }
    for (int mask = 1; mask <= 32; mask <<= 1) {
        pn += __shfl_xor(pn, mask); pq += __shfl_xor(pq, mask); pk += __shfl_xor(pk, mask);
    }
    if ((t & 63) == 0) { red[t >> 6] = pn; red[4 + (t >> 6)] = pq; red[8 + (t >> 6)] = pk; }
    __syncthreads();
    if (t == 0) {
        float nm = red[0] + red[1] + red[2] + red[3];
        float qq = red[4] + red[5] + red[6] + red[7];
        float kk = red[8] + red[9] + red[10] + red[11];
        float cosv = nm / (fmaxf(sqrtf(qq), 1e-8f) * fmaxf(sqrtf(kk), 1e-8f));
        atomicAdd(out, -cosv * (float)d / (256.0f * 1024.0f));
    }
}

// ---------------- launch ----------------
extern "C" void kernel_launch(void* const* d_in, const int* in_sizes, int n_in,
                              void* d_out, int out_size, void* d_ws, size_t ws_size,
                              hipStream_t stream) {
    (void)in_sizes; (void)n_in; (void)out_size; (void)ws_size;
    const float* query = (const float*)d_in[0];
    const float* keys  = (const float*)d_in[1];
    const float* R     = (const float*)d_in[2];
    float* out = (float*)d_out;
    char* ws = (char*)d_ws;

    unsigned long long* best = (unsigned long long*)ws;          // 14336 B (pad 16384)
    float* Qrot   = (float*)(ws + 16384);                        // 1 MiB
    u16*   Rpack  = (u16*)(ws + 16384 + 1048576);                // 2 MiB
    u16*   Qpack  = (u16*)(ws + 16384 + 1048576 + 2097152);      // 512 KiB

    hipMemsetAsync(best, 0, NU * BZn * sizeof(unsigned long long), stream);
    hipMemsetAsync(out, 0, sizeof(float), stream);

    k_qrot <<<64,  256, 0, stream>>>(query, R, Qrot);
    k_rpack<<<512, 256, 0, stream>>>(R, Rpack);
    k_qpack<<<128, 256, 0, stream>>>(Qrot, Qpack);

    hipFuncSetAttribute((const void*)k_main,
                        hipFuncAttributeMaxDynamicSharedMemorySize, LDS_TOT);
    k_main <<<MTOT / BM, 512, LDS_TOT, stream>>>(keys, Rpack, Qpack, best);
    k_final<<<NU * BZn, 256, 0, stream>>>(keys, R, Qrot, best, out);
}